// Round 8
// baseline (29449.313 us; speedup 1.0000x reference)
//
#include <hip/hip_runtime.h>
#include <hip/hip_bf16.h>
#include <hip/hip_cooperative_groups.h>
#include <cstdint>
#include <cstddef>

namespace cg = cooperative_groups;

// B=32, T=512, I=H=1024, L=2, gates 4H=4096. fp32 in/out.
// d_out fp32: outputs[32][512][1024] ++ h_n[2][32][1024] ++ c_n[2][32][1024].
// R7: persistent cooperative recurrence — per chunk: GEMM (G = x@Wx^T + b,
// bf16 MFMA, fp32 out) -> ONE cooperative kernel running Tc steps with
// grid.sync() between steps (c register-resident). 36 dispatches total.

typedef unsigned short ush;
typedef short bf16x8 __attribute__((ext_vector_type(8)));
typedef float f32x4 __attribute__((ext_vector_type(4)));

#define TT 512

__device__ __forceinline__ ush f2bf(float f) {
  __hip_bfloat16 h = __float2bfloat16(f);
  return *reinterpret_cast<ush*>(&h);
}
__device__ __forceinline__ float sigm(float x) { return 1.f / (1.f + __expf(-x)); }

// ---------------------------------------------------------------------------
// Whb[j][k] = bf16(W[j][1024+k]). grid 4096, 256 thr x 4.
// ---------------------------------------------------------------------------
__global__ __launch_bounds__(256) void cast_wh(const float* __restrict__ W,
                                               ush* __restrict__ Whb) {
  int j = blockIdx.x;
  int k = threadIdx.x * 4;
  float4 v = *(const float4*)(W + (size_t)j * 2048 + 1024 + k);
  ushort4 o;
  o.x = f2bf(v.x); o.y = f2bf(v.y); o.z = f2bf(v.z); o.w = f2bf(v.w);
  *(ushort4*)(Whb + (size_t)j * 1024 + k) = o;
}

__global__ __launch_bounds__(256) void zero64k(uint4* __restrict__ p) {
  p[blockIdx.x * 256 + threadIdx.x] = uint4{0, 0, 0, 0};
}

// ---------------------------------------------------------------------------
// 128x128 MFMA GEMM: G[r][j] = bias[j] + sum_{k<1024} A[r][k]*W[j][k].
// mode 0: A row r=(lt*32+b) -> x[b][t0+lt][*] fp32 (cvt in staging).
// mode 1: A = H0c bf16, row r contiguous.
// B = W fp32 rows j, stride 2048, x-half cols [0,1024).
// 256 thr = 4 waves (2x2 of 64x64), BK=64, LDS stride 88. grid(32, Tc/4).
// ---------------------------------------------------------------------------
__global__ __launch_bounds__(256) void gemm128(
    const float* __restrict__ xA, const ush* __restrict__ hA,
    const float* __restrict__ W, const float* __restrict__ bias,
    float* __restrict__ G, int mode, int t0) {
  __shared__ ush As[128][88];
  __shared__ ush Bs[128][88];
  int tid = threadIdx.x;
  int bn = blockIdx.x, bm = blockIdx.y;
  int srow = tid >> 1;
  int shalf = (tid & 1) * 32;
  int lane = tid & 63, quad = lane >> 4, l15 = lane & 15;
  int w = tid >> 6;
  int m_base = (w >> 1) * 64, n_base = (w & 1) * 64;

  int r = bm * 128 + srow;
  const float* axf = nullptr;
  const ush* axh = nullptr;
  if (mode == 0)
    axf = xA + ((size_t)(r & 31) * TT + t0 + (r >> 5)) * 1024;
  else
    axh = hA + (size_t)r * 1024;
  const float* wrow = W + (size_t)(bn * 128 + srow) * 2048;

  f32x4 acc[4][4];
#pragma unroll
  for (int i = 0; i < 4; ++i)
#pragma unroll
    for (int j = 0; j < 4; ++j) acc[i][j] = f32x4{0.f, 0.f, 0.f, 0.f};

  for (int k0 = 0; k0 < 1024; k0 += 64) {
    if (mode == 0) {
      const float* p = axf + k0 + shalf;
      ush* d = &As[srow][shalf];
#pragma unroll
      for (int s = 0; s < 8; ++s) {
        float4 v = ((const float4*)p)[s];
        ushort4 o;
        o.x = f2bf(v.x); o.y = f2bf(v.y); o.z = f2bf(v.z); o.w = f2bf(v.w);
        ((ushort4*)d)[s] = o;
      }
    } else {
      const uint4* p = (const uint4*)(axh + k0 + shalf);
      uint4* d = (uint4*)&As[srow][shalf];
#pragma unroll
      for (int s = 0; s < 4; ++s) d[s] = p[s];
    }
    {
      const float* p = wrow + k0 + shalf;
      ush* d = &Bs[srow][shalf];
#pragma unroll
      for (int s = 0; s < 8; ++s) {
        float4 v = ((const float4*)p)[s];
        ushort4 o;
        o.x = f2bf(v.x); o.y = f2bf(v.y); o.z = f2bf(v.z); o.w = f2bf(v.w);
        ((ushort4*)d)[s] = o;
      }
    }
    __syncthreads();
#pragma unroll
    for (int kc = 0; kc < 2; ++kc) {
      bf16x8 af[4], bf_[4];
#pragma unroll
      for (int i = 0; i < 4; ++i)
        af[i] = *(const bf16x8*)&As[m_base + i * 16 + l15][kc * 32 + quad * 8];
#pragma unroll
      for (int j = 0; j < 4; ++j)
        bf_[j] = *(const bf16x8*)&Bs[n_base + j * 16 + l15][kc * 32 + quad * 8];
#pragma unroll
      for (int i = 0; i < 4; ++i)
#pragma unroll
        for (int j = 0; j < 4; ++j)
          acc[i][j] = __builtin_amdgcn_mfma_f32_16x16x32_bf16(af[i], bf_[j],
                                                              acc[i][j], 0, 0, 0);
    }
    __syncthreads();
  }

#pragma unroll
  for (int j = 0; j < 4; ++j) {
    int col = bn * 128 + n_base + j * 16 + l15;
    float bj = bias[col];
#pragma unroll
    for (int i = 0; i < 4; ++i) {
      int row = bm * 128 + m_base + i * 16 + quad * 4;
#pragma unroll
      for (int reg = 0; reg < 4; ++reg)
        G[(size_t)(row + reg) * 4096 + col] = acc[i][j][reg] + bj;
    }
  }
}

// ---------------------------------------------------------------------------
// Persistent cooperative recurrence: Tc steps of one layer in ONE launch.
// 64 blocks (c-slice 16) x 512 thr = 8 waves (w = kh*4+g). Per step: MFMA
// partials (h_prev @ Wh^T) -> LDS combine -> fused pointwise (c in REGISTER
// across the whole chunk) -> write h slot -> grid.sync().
// layer 0: hring = H0c chunk ring (Tc slots; slot Tc-1 carries prev chunk).
// layer 1: hring = 2 ping-pong slots; also writes fp32 OUT rows.
// ---------------------------------------------------------------------------
__global__ __launch_bounds__(512) void lstm_seq(
    const float* __restrict__ G, const ush* __restrict__ Whb,
    ush* __restrict__ hring, const ush* __restrict__ zbuf,
    float* __restrict__ OUT, float* __restrict__ cst,
    float* __restrict__ hnf32, int t0, int Tc, int layer) {
  cg::grid_group grid = cg::this_grid();
  __shared__ float pg[8][32][16];  // [w=kh*4+g][b][c]
  int tid = threadIdx.x;
  int c0 = blockIdx.x * 16;
  int w = tid >> 6, lane = tid & 63, quad = lane >> 4, l15 = lane & 15;
  int g = w & 3, kh = w >> 2;
  int pb = tid >> 4, pc = tid & 15;  // pointwise (b, c)

  float creg = (t0 > 0) ? cst[pb * 1024 + c0 + pc] : 0.f;
  const ush* bp = Whb + (size_t)(g * 1024 + c0 + l15) * 1024 + kh * 512 + quad * 8;

  for (int lt = 0; lt < Tc; ++lt) {
    int t = t0 + lt;
    const ush* hprev;
    ush* hwrite;
    if (layer == 0) {
      hprev = (t == 0) ? zbuf
                       : hring + (size_t)((lt == 0) ? (Tc - 1) : (lt - 1)) * 32768;
      hwrite = hring + (size_t)lt * 32768;
    } else {
      hprev = (t == 0) ? zbuf : hring + (size_t)(1 - (t & 1)) * 32768;
      hwrite = hring + (size_t)(t & 1) * 32768;
    }

    f32x4 acc0 = {0.f, 0.f, 0.f, 0.f}, acc1 = {0.f, 0.f, 0.f, 0.f};
    const ush* ap0 = hprev + (size_t)l15 * 1024 + kh * 512 + quad * 8;
    const ush* ap1 = ap0 + 16 * 1024;
#pragma unroll
    for (int ch = 0; ch < 16; ++ch) {
      bf16x8 bv = *(const bf16x8*)(bp + ch * 32);
      bf16x8 a0 = *(const bf16x8*)(ap0 + ch * 32);
      bf16x8 a1 = *(const bf16x8*)(ap1 + ch * 32);
      acc0 = __builtin_amdgcn_mfma_f32_16x16x32_bf16(a0, bv, acc0, 0, 0, 0);
      acc1 = __builtin_amdgcn_mfma_f32_16x16x32_bf16(a1, bv, acc1, 0, 0, 0);
    }
#pragma unroll
    for (int reg = 0; reg < 4; ++reg) {
      pg[w][quad * 4 + reg][l15] = acc0[reg];
      pg[w][16 + quad * 4 + reg][l15] = acc1[reg];
    }
    __syncthreads();

    const float* grow = G + (size_t)(lt * 32 + pb) * 4096 + c0 + pc;
    float s0 = grow[0]    + pg[0][pb][pc] + pg[4][pb][pc];
    float s1 = grow[1024] + pg[1][pb][pc] + pg[5][pb][pc];
    float s2 = grow[2048] + pg[2][pb][pc] + pg[6][pb][pc];
    float s3 = grow[3072] + pg[3][pb][pc] + pg[7][pb][pc];
    float fg = sigm(s0), ig = sigm(s1), gv = tanhf(s2), og = sigm(s3);
    float cn = fg * creg + ig * gv;
    creg = cn;
    float hn = og * tanhf(cn);
    hwrite[pb * 1024 + c0 + pc] = f2bf(hn);
    if (layer == 1)
      OUT[(size_t)pb * TT * 1024 + (size_t)t * 1024 + c0 + pc] = hn;
    if (t == TT - 1) hnf32[pb * 1024 + c0 + pc] = hn;

    __threadfence();
    grid.sync();  // h visible to all blocks; pg safe to reuse
  }
  cst[pb * 1024 + c0 + pc] = creg;
}

// ---------------------------------------------------------------------------
// c_n copy (fp32). 65536 elements.
// ---------------------------------------------------------------------------
__global__ __launch_bounds__(256) void fin_c(const float* __restrict__ cst,
                                             float* __restrict__ dst) {
  int i = blockIdx.x * 256 + threadIdx.x;
  dst[i] = cst[i];
}

extern "C" void kernel_launch(void* const* d_in, const int* in_sizes, int n_in,
                              void* d_out, int out_size, void* d_ws, size_t ws_size,
                              hipStream_t stream) {
  const float* x = (const float*)d_in[0];
  const float* W0 = (const float*)d_in[1];
  const float* b0 = (const float*)d_in[2];
  const float* W1 = (const float*)d_in[3];
  const float* b1 = (const float*)d_in[4];
  float* OUT = (float*)d_out;

  // ws layout (bytes), identical to R6:
  //   Whb0 : 0 .. 8388608        Whb1 : 8388608 .. 16777216
  //   zbuf : 16777216 (64 KiB)   hs1 ring (2 slots): 16842752, 16908288
  //   cst  : 16973824 (256 KiB)  G: 17235968 (Tc*32*4096*4)  H0c after G
  int Tc = 4;
  {
    const int cand[5] = {64, 32, 16, 8, 4};
    for (int i = 0; i < 5; ++i) {
      size_t need = 17235968ull + (size_t)cand[i] * 32 * 4096 * 4 +
                    (size_t)cand[i] * 32 * 1024 * 2;
      if (need <= ws_size) { Tc = cand[i]; break; }
    }
  }
  char* ws = (char*)d_ws;
  ush* Whb0 = (ush*)ws;
  ush* Whb1 = (ush*)(ws + 8388608);
  ush* zbuf = (ush*)(ws + 16777216);
  ush* hs1 = (ush*)(ws + 16842752);   // 2 contiguous slots of 32768 ush
  float* cst0 = (float*)(ws + 16973824);
  float* cst1 = cst0 + 32768;
  float* G = (float*)(ws + 17235968);
  ush* H0c = (ush*)(ws + 17235968 + (size_t)Tc * 32 * 4096 * 4);

  cast_wh<<<4096, 256, 0, stream>>>(W0, Whb0);
  cast_wh<<<4096, 256, 0, stream>>>(W1, Whb1);
  zero64k<<<16, 256, 0, stream>>>((uint4*)zbuf);

  float* hn0 = OUT + 16777216;
  float* hn1 = OUT + 16777216 + 32768;
  dim3 ggrid(32, (unsigned)(Tc / 4));

  const int NCH = TT / Tc;
  for (int ch = 0; ch < NCH; ++ch) {
    int t0 = ch * Tc;
    gemm128<<<ggrid, 256, 0, stream>>>(x, nullptr, W0, b0, G, 0, t0);
    {
      const float* Ga = G; const ush* Wa = Whb0; ush* hr = H0c;
      const ush* zb = zbuf; float* Oa = OUT; float* ca = cst0; float* ha = hn0;
      int t0v = t0, Tcv = Tc, lv = 0;
      void* args[] = {&Ga, &Wa, &hr, &zb, &Oa, &ca, &ha, &t0v, &Tcv, &lv};
      hipLaunchCooperativeKernel(reinterpret_cast<void*>(lstm_seq), dim3(64),
                                 dim3(512), args, 0, stream);
    }
    gemm128<<<ggrid, 256, 0, stream>>>(nullptr, H0c, W1, b1, G, 1, t0);
    {
      const float* Ga = G; const ush* Wa = Whb1; ush* hr = hs1;
      const ush* zb = zbuf; float* Oa = OUT; float* ca = cst1; float* ha = hn1;
      int t0v = t0, Tcv = Tc, lv = 1;
      void* args[] = {&Ga, &Wa, &hr, &zb, &Oa, &ca, &ha, &t0v, &Tcv, &lv};
      hipLaunchCooperativeKernel(reinterpret_cast<void*>(lstm_seq), dim3(64),
                                 dim3(512), args, 0, stream);
    }
  }

  fin_c<<<256, 256, 0, stream>>>(cst0, OUT + 16777216 + 65536);
}